// Round 4
// baseline (403.318 us; speedup 1.0000x reference)
//
#include <hip/hip_runtime.h>

#define B_  4
#define S_  2048
#define D_  1024
#define H_  16
#define HD_ 64
#define M_  (B_*S_)   // 8192
#define QSCALE 0.1803368801111204f   // 0.125 * log2(e): folds softmax scale + exp2 base change

typedef unsigned short u16;
typedef __bf16 bf16x8 __attribute__((ext_vector_type(8)));
typedef __bf16 bf16x2 __attribute__((ext_vector_type(2)));
typedef float  f32x4  __attribute__((ext_vector_type(4)));
typedef float  f32x16 __attribute__((ext_vector_type(16)));

__device__ __forceinline__ u16 f2bf(float f) {
  unsigned int u = __float_as_uint(f);
  u += 0x7fffu + ((u >> 16) & 1u);
  return (u16)(u >> 16);
}
// packed f32x2 -> bf16x2 (single v_cvt_pk_bf16_f32 on gfx950)
__device__ __forceinline__ unsigned int packbf2(float lo, float hi) {
#if __has_builtin(__builtin_amdgcn_cvt_pk_bf16_f32)
  union { bf16x2 v; unsigned int u; } c;
  c.v = __builtin_amdgcn_cvt_pk_bf16_f32(lo, hi);
  return c.u;
#else
  return (unsigned int)f2bf(lo) | ((unsigned int)f2bf(hi) << 16);
#endif
}
// async global->LDS, 16B per lane; LDS dest = wave-uniform base + lane*16
__device__ __forceinline__ void gld16(const void* g, void* l) {
  __builtin_amdgcn_global_load_lds(
      (const __attribute__((address_space(1))) unsigned int*)g,
      (__attribute__((address_space(3))) unsigned int*)l, 16, 0, 0);
}
#define MFMA32(a,b,c) __builtin_amdgcn_mfma_f32_32x32x16_bf16(a,b,c,0,0,0)

// ---------------- convert x (fp32 -> bf16) ----------------
__global__ void cvt_f32_bf16(const float* __restrict__ in, u16* __restrict__ out, int n4) {
  int i = blockIdx.x * 256 + threadIdx.x;
  if (i < n4) {
    float4 v = ((const float4*)in)[i];
    ((uint2*)out)[i] = make_uint2(packbf2(v.x, v.y), packbf2(v.z, v.w));
  }
}

// ------------- transpose fp32 [R][C] -> bf16 [C][R] -------------------
__global__ void transpose_w(const float* __restrict__ in, u16* __restrict__ out, int R, int C) {
  __shared__ float tile[32][33];
  int c0 = blockIdx.x * 32, r0 = blockIdx.y * 32;
  int tx = threadIdx.x, ty = threadIdx.y;
  #pragma unroll
  for (int i = 0; i < 4; i++)
    tile[ty + i*8][tx] = in[(size_t)(r0 + ty + i*8) * C + c0 + tx];
  __syncthreads();
  #pragma unroll
  for (int i = 0; i < 4; i++)
    out[(size_t)(c0 + ty + i*8) * R + r0 + tx] = f2bf(tile[tx][ty + i*8]);
}

// ------------- transpose V bf16: [bh][2048][64] -> [bh][64][2048] -----
__global__ void transpose_v(const u16* __restrict__ in, u16* __restrict__ out) {
  __shared__ u16 tile[32][33];
  size_t base = (size_t)blockIdx.z * S_ * HD_;
  int c0 = blockIdx.x * 32, r0 = blockIdx.y * 32;
  int tx = threadIdx.x, ty = threadIdx.y;
  #pragma unroll
  for (int i = 0; i < 4; i++)
    tile[ty + i*8][tx] = in[base + (size_t)(r0 + ty + i*8) * HD_ + c0 + tx];
  __syncthreads();
  #pragma unroll
  for (int i = 0; i < 4; i++)
    out[base + (size_t)(c0 + ty + i*8) * S_ + r0 + tx] = tile[tx][ty + i*8];
}

// ---------------- QKV GEMM: [8192,1024]x[1024,3072], 32x32x16 MFMA ----
__global__ __launch_bounds__(256,2) void gemm_qkv(
    const u16* __restrict__ X, const u16* __restrict__ WT,
    const float* __restrict__ bias,
    u16* __restrict__ qb, u16* __restrict__ kb, u16* __restrict__ vb)
{
  __shared__ u16 As[16*512];  // 16 frags x 1KB (frag id = mf*4+kk)
  __shared__ u16 Bs[16*512];
  const int t = threadIdx.x, w = t >> 6, l = t & 63, l31 = l & 31, h = l >> 5;
  const int m0 = blockIdx.y * 128, n0 = blockIdx.x * 128;
  const u16* Arow = X  + (size_t)(m0 + w*32 + l31) * D_;
  const u16* Brow = WT + (size_t)(n0 + w*32 + l31) * D_;

  f32x16 acc[2][2] = {};
  for (int k0 = 0; k0 < D_; k0 += 64) {
    __syncthreads();
    #pragma unroll
    for (int kk = 0; kk < 4; kk++) {
      gld16(Arow + k0 + kk*16 + h*8, (char*)As + (w*4+kk)*1024);
      gld16(Brow + k0 + kk*16 + h*8, (char*)Bs + (w*4+kk)*1024);
    }
    __syncthreads();
    const int mfb = (w>>1)*2, nfb = (w&1)*2;
    #pragma unroll
    for (int kk = 0; kk < 4; kk++) {
      bf16x8 a0 = *(const bf16x8*)(As + ((mfb+0)*4+kk)*512 + l*8);
      bf16x8 a1 = *(const bf16x8*)(As + ((mfb+1)*4+kk)*512 + l*8);
      bf16x8 b0 = *(const bf16x8*)(Bs + ((nfb+0)*4+kk)*512 + l*8);
      bf16x8 b1 = *(const bf16x8*)(Bs + ((nfb+1)*4+kk)*512 + l*8);
      acc[0][0] = MFMA32(a0, b0, acc[0][0]);
      acc[0][1] = MFMA32(a0, b1, acc[0][1]);
      acc[1][0] = MFMA32(a1, b0, acc[1][0]);
      acc[1][1] = MFMA32(a1, b1, acc[1][1]);
    }
  }
  const int wm = (w>>1)*64, wn = (w&1)*64;
  #pragma unroll
  for (int mt = 0; mt < 2; mt++)
  #pragma unroll
  for (int nt = 0; nt < 2; nt++) {
    int n = n0 + wn + nt*32 + l31;
    float bia = bias[n];
    int which = n >> 10, hh = (n >> 6) & 15, hd = n & 63;
    #pragma unroll
    for (int r = 0; r < 16; r++) {
      int m = m0 + wm + mt*32 + (r&3) + 8*(r>>2) + 4*h;
      float v = acc[mt][nt][r] + bia;
      int bb = m >> 11, s = m & 2047;
      size_t idx = (((size_t)(bb*H_ + hh) * S_) + s) * HD_ + hd;
      if (which == 0)      qb[idx] = f2bf(v * QSCALE);
      else if (which == 1) kb[idx] = f2bf(v);
      else                 vb[idx] = f2bf(v);
    }
  }
}

// ---------------- proj GEMM: [8192,1024]x[1024,1024] + bias -> fp32 ---
__global__ __launch_bounds__(256,2) void gemm_proj(
    const u16* __restrict__ X, const u16* __restrict__ WT,
    const float* __restrict__ bias, float* __restrict__ out)
{
  __shared__ u16 As[16*512];
  __shared__ u16 Bs[16*512];
  const int t = threadIdx.x, w = t >> 6, l = t & 63, l31 = l & 31, h = l >> 5;
  const int m0 = blockIdx.y * 128, n0 = blockIdx.x * 128;
  const u16* Arow = X  + (size_t)(m0 + w*32 + l31) * D_;
  const u16* Brow = WT + (size_t)(n0 + w*32 + l31) * D_;

  f32x16 acc[2][2] = {};
  for (int k0 = 0; k0 < D_; k0 += 64) {
    __syncthreads();
    #pragma unroll
    for (int kk = 0; kk < 4; kk++) {
      gld16(Arow + k0 + kk*16 + h*8, (char*)As + (w*4+kk)*1024);
      gld16(Brow + k0 + kk*16 + h*8, (char*)Bs + (w*4+kk)*1024);
    }
    __syncthreads();
    const int mfb = (w>>1)*2, nfb = (w&1)*2;
    #pragma unroll
    for (int kk = 0; kk < 4; kk++) {
      bf16x8 a0 = *(const bf16x8*)(As + ((mfb+0)*4+kk)*512 + l*8);
      bf16x8 a1 = *(const bf16x8*)(As + ((mfb+1)*4+kk)*512 + l*8);
      bf16x8 b0 = *(const bf16x8*)(Bs + ((nfb+0)*4+kk)*512 + l*8);
      bf16x8 b1 = *(const bf16x8*)(Bs + ((nfb+1)*4+kk)*512 + l*8);
      acc[0][0] = MFMA32(a0, b0, acc[0][0]);
      acc[0][1] = MFMA32(a0, b1, acc[0][1]);
      acc[1][0] = MFMA32(a1, b0, acc[1][0]);
      acc[1][1] = MFMA32(a1, b1, acc[1][1]);
    }
  }
  const int wm = (w>>1)*64, wn = (w&1)*64;
  #pragma unroll
  for (int mt = 0; mt < 2; mt++)
  #pragma unroll
  for (int nt = 0; nt < 2; nt++) {
    int n = n0 + wn + nt*32 + l31;
    float bia = bias[n];
    #pragma unroll
    for (int r = 0; r < 16; r++) {
      int m = m0 + wm + mt*32 + (r&3) + 8*(r>>2) + 4*h;
      out[(size_t)m * D_ + n] = acc[mt][nt][r] + bia;
    }
  }
}

// ---------------- flash attention (S^T trick, 32x32x16) ---------------
// grid (S/64, B*H), 128 threads (2 waves). Wave w owns 32 q-rows.
// q,k: [bh][S][64] bf16 (q pre-scaled by QSCALE). vt: [bh][64][S] bf16.
__global__ __launch_bounds__(128,4) void attn(
    const u16* __restrict__ qb, const u16* __restrict__ kb,
    const u16* __restrict__ vt, u16* __restrict__ ob)
{
  __shared__ u16 Kl[8*512];       // K-tile 64 keys x 64 hd, frag-major (mt*4+kk)
  __shared__ u16 Vl[8*512];       // V-tile 64 hd x 64 keys, frag-major (nt*4+kk2)
  __shared__ float redL[2][32];   // per-wave alpha / 1/l broadcast
  const int t = threadIdx.x, w = t >> 6, l = t & 63, l31 = l & 31, h = l >> 5;
  const int bh = blockIdx.y, b = bh >> 4, hh = bh & 15;
  const int s0 = blockIdx.x * 64 + w * 32;
  const u16* qp = qb + (size_t)bh * S_ * HD_;
  const u16* kp = kb + (size_t)bh * S_ * HD_;
  const u16* vp = vt + (size_t)bh * HD_ * S_;

  // Q B-frags, resident: qrow = s0+l31, hd = kk*16+h*8+j
  bf16x8 qa[4];
  #pragma unroll
  for (int kk = 0; kk < 4; kk++)
    qa[kk] = *(const bf16x8*)(qp + (size_t)(s0 + l31)*HD_ + kk*16 + h*8);

  f32x16 o[2] = {};
  float m_ = -1e30f, l_ = 0.f;

  for (int k0 = 0; k0 < S_; k0 += 64) {
    __syncthreads();
    #pragma unroll
    for (int j = 0; j < 4; j++) {
      gld16(kp + (size_t)(k0 + w*32 + l31)*HD_ + j*16 + h*8, (char*)Kl + (w*4+j)*1024);
      gld16(vp + (size_t)(w*32 + l31)*S_ + k0 + j*16 + h*8, (char*)Vl + (w*4+j)*1024);
    }
    __syncthreads();

    // S^T = K * Q^T : sf[mt], D[m=key mt*32+(r&3)+8*(r>>2)+4h][n=qrow l31]
    f32x16 sf[2] = {};
    #pragma unroll
    for (int kk = 0; kk < 4; kk++) {
      bf16x8 ka0 = *(const bf16x8*)(Kl + (0*4+kk)*512 + l*8);
      bf16x8 ka1 = *(const bf16x8*)(Kl + (1*4+kk)*512 + l*8);
      sf[0] = MFMA32(ka0, qa[kk], sf[0]);
      sf[1] = MFMA32(ka1, qa[kk], sf[1]);
    }

    // online softmax for this lane's q-row (l31); keys split across h-halves
    float mx8[8];
    #pragma unroll
    for (int r = 0; r < 8; r++)
      mx8[r] = fmaxf(fmaxf(sf[0][r], sf[0][r+8]), fmaxf(sf[1][r], sf[1][r+8]));
    #pragma unroll
    for (int st = 4; st >= 1; st >>= 1)
      #pragma unroll
      for (int r = 0; r < st; r++) mx8[r] = fmaxf(mx8[r], mx8[r+st]);
    float tm = fmaxf(mx8[0], __shfl_xor(mx8[0], 32));
    float mn = fmaxf(m_, tm);
    float alpha = __builtin_amdgcn_exp2f(m_ - mn);
    m_ = mn;
    float sa = 0.f, sb = 0.f, sc = 0.f, sd = 0.f;
    #pragma unroll
    for (int mt = 0; mt < 2; mt++)
      #pragma unroll
      for (int r = 0; r < 16; r += 4) {
        float p0 = __builtin_amdgcn_exp2f(sf[mt][r+0] - mn);
        float p1 = __builtin_amdgcn_exp2f(sf[mt][r+1] - mn);
        float p2 = __builtin_amdgcn_exp2f(sf[mt][r+2] - mn);
        float p3 = __builtin_amdgcn_exp2f(sf[mt][r+3] - mn);
        sf[mt][r+0] = p0; sf[mt][r+1] = p1; sf[mt][r+2] = p2; sf[mt][r+3] = p3;
        sa += p0; sb += p1; sc += p2; sd += p3;
      }
    float s = (sa + sb) + (sc + sd);
    s += __shfl_xor(s, 32);
    l_ = l_ * alpha + s;

    // rescale O by alpha (row of o reg r = 8*(r>>2)+4h+(r&3); broadcast via LDS)
    redL[w][l31] = alpha;
    __builtin_amdgcn_s_waitcnt(0);  // lgkmcnt(0) for same-wave LDS RAW
    #pragma unroll
    for (int rb = 0; rb < 4; rb++) {
      f32x4 a4 = *(const f32x4*)&redL[w][8*rb + 4*h];
      #pragma unroll
      for (int c = 0; c < 4; c++) {
        int r = rb*4 + c;
        o[0][r] *= a4[c];
        o[1][r] *= a4[c];
      }
    }

    // pack P: pk[mt][e][f] = keys mt*32+8e+4h+2f+{0,1} (qrow l31)
    unsigned int pk[2][4][2];
    #pragma unroll
    for (int mt = 0; mt < 2; mt++)
      #pragma unroll
      for (int e = 0; e < 4; e++)
        #pragma unroll
        for (int f = 0; f < 2; f++)
          pk[mt][e][f] = packbf2(sf[mt][4*e + 2*f], sf[mt][4*e + 2*f + 1]);

    // O += P*V ; P A-frag assembled via half-wave exchange
    #pragma unroll
    for (int kk2 = 0; kk2 < 4; kk2++) {
      const int mt = kk2 >> 1, k1 = kk2 & 1;
      bf16x8 bv0 = *(const bf16x8*)(Vl + (0*4+kk2)*512 + l*8);
      bf16x8 bv1 = *(const bf16x8*)(Vl + (1*4+kk2)*512 + l*8);
      unsigned int s0_ = h ? pk[mt][2*k1][0] : pk[mt][2*k1+1][0];
      unsigned int s1_ = h ? pk[mt][2*k1][1] : pk[mt][2*k1+1][1];
      unsigned int r0 = (unsigned int)__shfl_xor((int)s0_, 32);
      unsigned int r1 = (unsigned int)__shfl_xor((int)s1_, 32);
      union { unsigned int u[4]; bf16x8 v; } pa;
      pa.u[0] = h ? r0 : pk[mt][2*k1][0];
      pa.u[1] = h ? r1 : pk[mt][2*k1][1];
      pa.u[2] = h ? pk[mt][2*k1+1][0] : r0;
      pa.u[3] = h ? pk[mt][2*k1+1][1] : r1;
      o[0] = MFMA32(pa.v, bv0, o[0]);
      o[1] = MFMA32(pa.v, bv1, o[1]);
    }
  }

  // epilogue: normalize by 1/l (broadcast), write bf16 [token][h*64+hd]
  redL[w][l31] = 1.f / l_;
  __builtin_amdgcn_s_waitcnt(0);
  #pragma unroll
  for (int rb = 0; rb < 4; rb++) {
    f32x4 iv4 = *(const f32x4*)&redL[w][8*rb + 4*h];
    #pragma unroll
    for (int c = 0; c < 4; c++) {
      int r = rb*4 + c;
      int row = s0 + c + 8*rb + 4*h;
      size_t off = ((size_t)(b*S_ + row)) * D_ + hh*64;
      ob[off + 0*32 + l31] = f2bf(o[0][r] * iv4[c]);
      ob[off + 1*32 + l31] = f2bf(o[1][r] * iv4[c]);
    }
  }
}

extern "C" void kernel_launch(void* const* d_in, const int* in_sizes, int n_in,
                              void* d_out, int out_size, void* d_ws, size_t ws_size,
                              hipStream_t stream) {
  const float* x      = (const float*)d_in[0];
  const float* w_qkv  = (const float*)d_in[1];
  const float* b_qkv  = (const float*)d_in[2];
  const float* w_proj = (const float*)d_in[3];
  const float* b_proj = (const float*)d_in[4];
  float* out = (float*)d_out;

  char* ws = (char*)d_ws;
  u16* xbf    = (u16*)ws; ws += (size_t)M_ * D_ * 2;
  u16* wqkvT  = (u16*)ws; ws += (size_t)3 * D_ * D_ * 2;
  u16* wprojT = (u16*)ws; ws += (size_t)D_ * D_ * 2;
  u16* qbuf   = (u16*)ws; ws += (size_t)M_ * D_ * 2;
  u16* kbuf   = (u16*)ws; ws += (size_t)M_ * D_ * 2;
  u16* vbuf   = (u16*)ws; ws += (size_t)M_ * D_ * 2;
  u16* vtbuf  = (u16*)ws; ws += (size_t)M_ * D_ * 2;
  u16* aobuf  = (u16*)ws; ws += (size_t)M_ * D_ * 2;

  cvt_f32_bf16<<<(M_ * D_ / 4 + 255) / 256, 256, 0, stream>>>(x, xbf, M_ * D_ / 4);
  transpose_w<<<dim3(3 * D_ / 32, D_ / 32), dim3(32, 8), 0, stream>>>(w_qkv, wqkvT, D_, 3 * D_);
  transpose_w<<<dim3(D_ / 32, D_ / 32), dim3(32, 8), 0, stream>>>(w_proj, wprojT, D_, D_);
  gemm_qkv<<<dim3(3 * D_ / 128, M_ / 128), 256, 0, stream>>>(xbf, wqkvT, b_qkv, qbuf, kbuf, vbuf);
  transpose_v<<<dim3(HD_ / 32, S_ / 32, B_ * H_), dim3(32, 8), 0, stream>>>(vbuf, vtbuf);
  attn<<<dim3(S_ / 64, B_ * H_), 128, 0, stream>>>(qbuf, kbuf, vtbuf, aobuf);
  gemm_proj<<<dim3(D_ / 128, M_ / 128), 256, 0, stream>>>(aobuf, wprojT, b_proj, out);
}